// Round 20
// baseline (242.627 us; speedup 1.0000x reference)
//
#include <hip/hip_runtime.h>
#include <math.h>

#define NB 256
#define NT 128
#define NDW 300
#define NH 128
#define NTYPE 8
#define NLEVEL 13
#define NN (NB*NT)

typedef __attribute__((ext_vector_type(8))) short short8;
typedef __attribute__((ext_vector_type(4))) float f32x4;

__device__ __forceinline__ unsigned int pack_bf16(float a, float b) {
  unsigned int ua = __float_as_uint(a); ua += 0x7fff + ((ua >> 16) & 1);
  unsigned int ub = __float_as_uint(b); ub += 0x7fff + ((ub >> 16) & 1);
  return (ua >> 16) | (ub & 0xffff0000u);
}
__device__ __forceinline__ float bflo(unsigned int u) { return __uint_as_float(u << 16); }
__device__ __forceinline__ float bfhi(unsigned int u) { return __uint_as_float(u & 0xffff0000u); }

// fast tanh: 1 - 2*rcp(e^{2x}+1); exact at +/-inf, ~1e-6 abs error
__device__ __forceinline__ float ftanh(float x) {
  float e = __expf(2.0f * x);
  return 1.0f - 2.0f * __builtin_amdgcn_rcpf(e + 1.0f);
}

// one packed-bf16 dot2: acc += w.lo*v.lo + w.hi*v.hi  (VOP3P, CDNA2+)
__device__ __forceinline__ float dot2a(unsigned int w, unsigned int v, float acc) {
  float r;
  asm("v_dot2_f32_bf16 %0, %1, %2, %3" : "=v"(r) : "v"(w), "v"(v), "v"(acc));
  return r;
}

// Transposed-packed bf16 weights: bwT[mat][d4][row] = uint2 of 4 bf16 =
// W[mat][row][4*d4..4*d4+3]. mat 0 = W_hr, mat 1+t = W_rel[t]. Coalesced build.
__global__ __launch_bounds__(256) void wcvt_kernel(const float* __restrict__ Whr,
    const float* __restrict__ Wrel, uint2* __restrict__ bwT) {
  int flat = blockIdx.x*256 + threadIdx.x;     // 0 .. 9*4096-1
  int mat = flat >> 12, rem = flat & 4095;
  int d4 = rem >> 7, row = rem & 127;
  const float* src = (mat == 0) ? &Whr[row*NH + d4*4]
                                : &Wrel[(size_t)(mat-1)*NH*NH + row*NH + d4*4];
  float4 v = *(const float4*)src;
  uint2 u; u.x = pack_bf16(v.x, v.y); u.y = pack_bf16(v.z, v.w);
  bwT[flat] = u;
}

// wx = token_emb @ W_wh.T via MFMA bf16. Tile 64m x 128n, K chunks of 32 (300 pad 320).
__global__ __launch_bounds__(256) void wx_kernel(const float* __restrict__ x,
    const float* __restrict__ Wwh, float* __restrict__ wx) {
  __shared__ __align__(16) unsigned int sA[64*16];    // [row][16 uints] = 32 bf16/row
  __shared__ __align__(16) unsigned int sB[128*16];
  int tid = threadIdx.x;
  int wave = tid >> 6, lane = tid & 63;
  size_t rowbase = (size_t)blockIdx.x * 64;
  f32x4 acc[8];
  #pragma unroll
  for (int ni = 0; ni < 8; ni++) acc[ni] = (f32x4){0.f,0.f,0.f,0.f};
  for (int kc = 0; kc < 320; kc += 32) {
    __syncthreads();
    #pragma unroll
    for (int q = 0; q < 2; q++) {             // stage A: 64 rows x 8 float4
      int flat = tid + q*256; int r = flat >> 3, f4 = flat & 7;
      int k0 = kc + f4*4;
      float4 v = make_float4(0.f,0.f,0.f,0.f);
      if (k0 + 3 < NDW) v = *(const float4*)&x[(rowbase + r)*NDW + k0];
      uint2 u; u.x = pack_bf16(v.x, v.y); u.y = pack_bf16(v.z, v.w);
      *(uint2*)&sA[r*16 + f4*2] = u;
    }
    #pragma unroll
    for (int q = 0; q < 4; q++) {             // stage B: 128 rows x 8 float4
      int flat = tid + q*256; int r = flat >> 3, f4 = flat & 7;
      int k0 = kc + f4*4;
      float4 v = make_float4(0.f,0.f,0.f,0.f);
      if (k0 + 3 < NDW) v = *(const float4*)&Wwh[(size_t)r*NDW + k0];
      uint2 u; u.x = pack_bf16(v.x, v.y); u.y = pack_bf16(v.z, v.w);
      *(uint2*)&sB[r*16 + f4*2] = u;
    }
    __syncthreads();
    short8 a = *(const short8*)&sA[(wave*16 + (lane & 15))*16 + (lane >> 4)*4];
    #pragma unroll
    for (int ni = 0; ni < 8; ni++) {
      short8 b = *(const short8*)&sB[(ni*16 + (lane & 15))*16 + (lane >> 4)*4];
      acc[ni] = __builtin_amdgcn_mfma_f32_16x16x32_bf16(a, b, acc[ni], 0, 0, 0);
    }
  }
  int rbase = wave*16 + (lane >> 4)*4;
  #pragma unroll
  for (int ni = 0; ni < 8; ni++)
    #pragma unroll
    for (int reg = 0; reg < 4; reg++)
      wx[(rowbase + rbase + reg)*NH + ni*16 + (lane & 15)] = acc[ni][reg];
}

// 4-node batched matvec, dot2 pipe. Weight stream wt (LDS or global, same code):
// lane owns output rows 2l, 2l+1; vectors are packed-bf16 panels (broadcast reads).
__device__ __forceinline__ void matvec4_d2(const uint2* __restrict__ wt,
    int lane, const unsigned int (*sv)[64], float* o0, float* o1) {
  #pragma unroll
  for (int j = 0; j < 4; j++) { o0[j] = 0.f; o1[j] = 0.f; }
  #pragma unroll 8
  for (int d4 = 0; d4 < 32; d4++) {
    uint4 u = *(const uint4*)&wt[d4*128 + 2*lane];   // rows 2l (x,y), 2l+1 (z,w)
    #pragma unroll
    for (int j = 0; j < 4; j++) {
      uint2 vv = *(const uint2*)&sv[j][d4*2];        // wave-uniform broadcast
      o0[j] = dot2a(u.x, vv.x, o0[j]);
      o0[j] = dot2a(u.y, vv.y, o0[j]);
      o1[j] = dot2a(u.z, vv.x, o1[j]);
      o1[j] = dot2a(u.w, vv.y, o1[j]);
    }
  }
}

// Mixed-type variant: per-node weight pointers (duplicate rows hit L1).
__device__ __forceinline__ void matvec4_d2mixed(const uint2* __restrict__ bwT,
    const int* tj, int lane, const unsigned int (*sv)[64], float* o0, float* o1) {
  const uint2* wt0 = bwT + (size_t)(1 + tj[0])*4096;
  const uint2* wt1 = bwT + (size_t)(1 + tj[1])*4096;
  const uint2* wt2 = bwT + (size_t)(1 + tj[2])*4096;
  const uint2* wt3 = bwT + (size_t)(1 + tj[3])*4096;
  #pragma unroll
  for (int j = 0; j < 4; j++) { o0[j] = 0.f; o1[j] = 0.f; }
  #pragma unroll 4
  for (int d4 = 0; d4 < 32; d4++) {
    int off = d4*128 + 2*lane;
    uint4 uu[4];
    uu[0] = *(const uint4*)&wt0[off];
    uu[1] = *(const uint4*)&wt1[off];
    uu[2] = *(const uint4*)&wt2[off];
    uu[3] = *(const uint4*)&wt3[off];
    #pragma unroll
    for (int j = 0; j < 4; j++) {
      uint2 vv = *(const uint2*)&sv[j][d4*2];
      o0[j] = dot2a(uu[j].x, vv.x, o0[j]);
      o0[j] = dot2a(uu[j].y, vv.y, o0[j]);
      o1[j] = dot2a(uu[j].z, vv.x, o1[j]);
      o1[j] = dot2a(uu[j].w, vv.y, o1[j]);
    }
  }
}

// One block per sentence, 1024 threads = 16 waves. All 13 levels in-block.
// WHOLE working set in LDS: sentence wx (packed bf16, 32KB) + W_hr (32KB) +
// seg accumulators (64KB) + bf16 panels (16KB). Per-batch global traffic =
// W_rel[t] stream only (L2-hot). Level-wide dynamic batch pool over 16 waves.
__global__ __launch_bounds__(1024) void tree_kernel(
    const uint2* __restrict__ bwT, const float* __restrict__ bwh,
    const float* __restrict__ wx, const int* __restrict__ parent,
    const int* __restrict__ dep_type, const int* __restrict__ height,
    float* __restrict__ hbuf) {
  __shared__ float sseg[NT][NH];                  // 64 KB seg accumulators
  __shared__ __align__(16) unsigned int swx[NT][64];    // 32 KB wx packed bf16
  __shared__ __align__(16) unsigned int ssh[16][4][64]; // 16 KB bf16 panels
  __shared__ __align__(16) uint2 sWhr[4096];      // 32 KB W_hr bf16
  __shared__ int sord[NT], par_l[NT], typ_l[NT];
  __shared__ int gs[105], fill[104], hist[104];
  int b = blockIdx.x, tid = threadIdx.x;
  int wave = tid >> 6, lane = tid & 63;
  int e0 = 2*lane;
  const float* wxb = wx + (size_t)b*NT*NH;
  float* hb = hbuf + (size_t)b*NT*NH;
  for (int idx = tid; idx < NT*NH/4; idx += 1024)
    ((float4*)sseg)[idx] = make_float4(0.f,0.f,0.f,0.f);
  for (int idx = tid; idx < 4096; idx += 1024)
    sWhr[idx] = bwT[idx];                         // stage W_hr once per block
  for (int idx = tid; idx < NT*64; idx += 1024) { // stage wx once (bf16 packed)
    int r = idx >> 6, c = idx & 63;
    float2 v = *(const float2*)&wxb[(size_t)r*NH + c*2];
    swx[r][c] = pack_bf16(v.x, v.y);
  }
  if (tid < 104) hist[tid] = 0;
  __syncthreads();
  int mykey = 0;
  if (tid < NT) {
    int g = b*NT + tid;
    int ty = dep_type[g];
    typ_l[tid] = ty;
    mykey = height[g]*NTYPE + ty;
    par_l[tid] = parent[g];
    atomicAdd(&hist[mykey], 1);                   // LDS atomic
  }
  __syncthreads();
  if (tid == 0) {
    int acc = 0;
    for (int u = 0; u < 104; u++) { gs[u] = acc; acc += hist[u]; }
    gs[104] = acc;
  }
  __syncthreads();
  if (tid < 104) fill[tid] = gs[tid];
  __syncthreads();
  if (tid < NT) {
    int pos = atomicAdd(&fill[mykey], 1);         // LDS atomic
    sord[pos] = tid;
  }
  float2 bv = *(const float2*)&bwh[e0];
  __syncthreads();
  for (int k = 0; k < NLEVEL; k++) {
    int ls = gs[k*NTYPE], le = gs[k*NTYPE + NTYPE];
    int nbat = (le - ls + 3) >> 2;
    for (int bi = wave; bi < nbat; bi += 16) {    // dynamic pool over all waves
      int base = ls + bi*4;
      int cnt = le - base; if (cnt > 4) cnt = 4;
      int nl[4], pl[4], tj[4];
      #pragma unroll
      for (int j = 0; j < 4; j++) {
        int it = base + j; if (it >= le) it = le - 1;   // clamp tail
        nl[j] = sord[it];
        pl[j] = par_l[nl[j]];
        tj[j] = typ_l[nl[j]];
      }
      // all gathers now LDS: own wx, parent wx (bf16), seg (fp32)
      unsigned int wq[4], pq[4];
      float2 sg[4];
      #pragma unroll
      for (int j = 0; j < 4; j++) wq[j] = swx[nl[j]][lane];
      #pragma unroll
      for (int j = 0; j < 4; j++) {
        int p = pl[j] >= 0 ? pl[j] : nl[j];
        pq[j] = swx[p][lane];
      }
      #pragma unroll
      for (int j = 0; j < 4; j++) sg[j] = *(const float2*)&sseg[nl[j]][e0];
      // finalize h -> global (fp32) + bf16 panel
      #pragma unroll
      for (int j = 0; j < 4; j++) {
        float s0 = ftanh(bflo(wq[j]) + bv.x);
        float s1 = ftanh(bfhi(wq[j]) + bv.y);
        float h0, h1;
        if (k == 0) { h0 = s0; h1 = s1; }
        else { h0 = ftanh(sg[j].x + s0); h1 = ftanh(sg[j].y + s1); }
        if (j < cnt)
          *(float2*)&hb[(size_t)nl[j]*NH + e0] = make_float2(h0, h1);  // final h
        ssh[wave][j][lane] = pack_bf16(h0, h1);   // wave-synchronous LDS
      }
      // matvec1: g = W_hr . h  (LDS weights, dot2 pipe)
      float g0v[4], g1v[4];
      matvec4_d2(sWhr, lane, ssh[wave], g0v, g1v);
      #pragma unroll
      for (int j = 0; j < 4; j++) {               // r = tanh(g + wx_parent)
        float r0 = ftanh(g0v[j] + bflo(pq[j]));
        float r1 = ftanh(g1v[j] + bfhi(pq[j]));
        ssh[wave][j][lane] = pack_bf16(r0, r1);
      }
      // matvec2: infl = W_rel[t] . r  (global weights, L2-hot)
      float o0[4], o1[4];
      bool pure = (tj[0] == tj[1]) & (tj[1] == tj[2]) & (tj[2] == tj[3]);
      if (pure)
        matvec4_d2(bwT + (size_t)(1 + tj[0])*4096, lane, ssh[wave], o0, o1);
      else
        matvec4_d2mixed(bwT, tj, lane, ssh[wave], o0, o1);
      #pragma unroll
      for (int j = 0; j < 4; j++) if (j < cnt && pl[j] >= 0) {
        atomicAdd(&sseg[pl[j]][e0],     o0[j]);   // LDS atomic (in-CU)
        atomicAdd(&sseg[pl[j]][e0 + 1], o1[j]);
      }
    }
    __syncthreads();                              // level boundary (block-local)
  }
}

extern "C" void kernel_launch(void* const* d_in, const int* in_sizes, int n_in,
                              void* d_out, int out_size, void* d_ws, size_t ws_size,
                              hipStream_t stream) {
  const float* token  = (const float*)d_in[0];
  const float* Wwh    = (const float*)d_in[1];
  const float* bwh    = (const float*)d_in[2];
  const float* Whr    = (const float*)d_in[3];
  const float* Wrel   = (const float*)d_in[4];
  const int*   parent = (const int*)d_in[5];
  const int*   dep    = (const int*)d_in[6];
  const int*   height = (const int*)d_in[7];

  float* hbuf = (float*)d_out;                          // final h (write-once)
  float* wx   = (float*)d_ws;                           // [NN,NH] f32, 16MB
  uint2* bwT  = (uint2*)((char*)d_ws + 16777216);       // 288KB bf16 weights

  wcvt_kernel<<<144, 256, 0, stream>>>(Whr, Wrel, bwT);
  wx_kernel<<<NN/64, 256, 0, stream>>>(token, Wwh, wx);
  tree_kernel<<<NB, 1024, 0, stream>>>(bwT, bwh, wx, parent, dep, height, hbuf);
}